// Round 9
// baseline (181.548 us; speedup 1.0000x reference)
//
#include <hip/hip_runtime.h>
#include <hip/hip_bf16.h>
#include <stdint.h>

typedef short bf16x8 __attribute__((ext_vector_type(8)));
typedef float f32x16 __attribute__((ext_vector_type(16)));

#define T 2048
#define KLEN 2049
#define DK 32
#define NCO 32
#define NCI 32
#define NB 32

#define GR 2216          // padded reversed row length (K=4 chain window reach)
#define SREF 2055        // x[s] lives at g = SREF - s (xr); xrs[g] = xr[g+1]
#define WT_CH 257        // 8-wide d-chunks, d in [0,2056)
#define WT_ELEMS (NCI*WT_CH*NCO*8)
#define XR_ELEMS (NB*NCI*GR)

#define WT_OFF 0
#define XR_OFF (WT_ELEMS*2)
#define XRS_OFF (XR_OFF + XR_ELEMS*2)

#define CIB 400          // bytes per ci row: 25 x 16B granules (200 elems)
#define CPYB 13376       // parity-copy stride: 12800 data + pad, ==64 mod 128 (bank de-alias)
#define BUFB 27264       // per double-buffer stride
#define RED_OFF (2*BUFB) // 54528: dedicated 16KB reduce area
#define LDS_TOT (RED_OFF + 16384)   // 70912 B -> 2 blocks/CU

// ---------------- kernel-generation: SIREN -> flipped, fragment-layout W ----
__global__ __launch_bounds__(256) void gen_w(
    const float* __restrict__ rel_pos,
    const float* __restrict__ w1, const float* __restrict__ b1, const float* __restrict__ om1,
    const float* __restrict__ w2, const float* __restrict__ b2, const float* __restrict__ om2,
    const float* __restrict__ w3, const float* __restrict__ b3,
    uint16_t* __restrict__ Wt)
{
    int d = blockIdx.x;          // flipped lag, 0..2055
    int tid = threadIdx.x;
    if (d >= KLEN) {             // zero pad region
        for (int r = 0; r < 4; ++r) {
            int coci = tid + 256*r;
            int co = coci >> 5, ci = coci & 31;
            Wt[(((ci*WT_CH + (d>>3))*NCO + co)<<3) + (d&7)] = 0;
        }
        return;
    }
    int kk = 2048 - d;
    float pos = rel_pos[kk];
    __shared__ float h1[DK];
    __shared__ float h2[DK];
    if (tid < DK) h1[tid] = sinf(om1[0]*(w1[tid]*pos + b1[tid]));
    __syncthreads();
    if (tid < DK) {
        float a = b2[tid];
        for (int j = 0; j < DK; ++j) a += w2[tid*DK+j]*h1[j];
        h2[tid] = sinf(om2[0]*a);
    }
    __syncthreads();
    for (int r = 0; r < 4; ++r) {
        int coci = tid + 256*r;
        float a = b3[coci];
        for (int j = 0; j < DK; ++j) a += w3[coci*DK+j]*h2[j];
        int co = coci >> 5, ci = coci & 31;
        __hip_bfloat16 hv = __float2bfloat16(a);
        Wt[(((ci*WT_CH + (d>>3))*NCO + co)<<3) + (d&7)] = *(uint16_t*)&hv;
    }
}

// ---------------- x -> reversed, zero-padded bf16 (plus shifted copy) -------
__global__ __launch_bounds__(256) void gen_x(const float* __restrict__ x,
                                             uint16_t* __restrict__ xr,
                                             uint16_t* __restrict__ xrs)
{
    int idx = blockIdx.x*256 + threadIdx.x;
    if (idx >= NB*NCI*GR) return;
    int row = idx / GR;          // b*32+ci
    int g = idx - row*GR;
    int s = SREF - g;
    float v  = (s  >= 0 && s  < T) ? x[row*T + s]  : 0.f;
    int s2 = s - 1;              // value at g+1
    float v2 = (s2 >= 0 && s2 < T) ? x[row*T + s2] : 0.f;
    __hip_bfloat16 hv = __float2bfloat16(v);
    __hip_bfloat16 hv2 = __float2bfloat16(v2);
    xr[idx]  = *(uint16_t*)&hv;
    xrs[idx] = *(uint16_t*)&hv2;
}

__device__ __forceinline__ void gld16(const uint16_t* g, char* l)
{
    typedef const __attribute__((address_space(1))) uint32_t GU;
    typedef __attribute__((address_space(3))) uint32_t LU;
    __builtin_amdgcn_global_load_lds((GU*)g, (LU*)l, 16, 0, 0);
}

// ---------------- causal conv: implicit-Toeplitz MFMA GEMM, K=4 tau-chain ---
// One chain per block; grid 512 = 2 blocks/CU. Pairing: blockIdx c and c+256
// carry chains of the SAME p (lengths 32-2p and 2p+2, sum 34) so co-resident
// blocks balance. b in low 5 bits keeps all blocks of a batch on one XCD.
// Double-buffered DMA staging (global_load_lds), one barrier per window.
__global__ __launch_bounds__(512, 4) void conv(
    const uint16_t* __restrict__ Wt, const uint16_t* __restrict__ xr,
    const float* __restrict__ bias, float* __restrict__ out)
{
    __shared__ uint4 lds4[LDS_TOT/16];
    char* ldsb = (char*)lds4;
    float* red = (float*)(ldsb + RED_OFF);
    int tid = threadIdx.x;
    int b = blockIdx.x & 31;
    int q = blockIdx.x >> 5;              // 0..15
    int p = q & 7;
    int th = (q < 8) ? (63 - (p << 2)) : ((p << 2) + 3);   // long B / short A
    int u = (th - 1) >> 1;                                 // windows = u+1
    int g0base = 2016 - (th << 5);
    int w = tid >> 6, lane = tid & 63, n = lane & 31, hi = lane >> 5;
    int cig = w;

    // staging: 1664 idx = 2 copies x 832 (800 real granules + 32 pad).
    int srcE[4], dstC[4];
    #pragma unroll
    for (int k = 0; k < 4; ++k) {
        int idxbase = (k < 3) ? (k*512 + w*64) : (1536 + w*64);
        int cpy = idxbase >= 832;
        int j0 = idxbase - cpy*832;
        dstC[k] = cpy*CPYB + (j0 << 4);
        int j = j0 + lane;
        if (j < 800) {
            int ci = (j*2622) >> 16;         // j/25
            int qq = j - ci*25;
            srcE[k] = (cpy ? XR_ELEMS : 0) + (b*NCI + ci)*GR + (qq << 3);
        } else srcE[k] = 0;                  // pad lane: safe dummy source
    }

    // B-read base: o = (39 - n + 8*hi) + 16*MM; byte = ci*CIB + par*CPYB + 2*(o-par)
    int obase = 39 - n + (hi << 3);
    int par = obase & 1;
    int bbb = cig*CIB + par*CPYB + ((obase - par) << 1);

    f32x16 acc0, acc1, acc2, acc3;
    #pragma unroll
    for (int r = 0; r < 16; ++r) { acc0[r]=0.f; acc1[r]=0.f; acc2[r]=0.f; acc3[r]=0.f; }

    // prologue: DMA window 0 into buf0
    #pragma unroll
    for (int k = 0; k < 3; ++k)
        gld16(xr + srcE[k] + g0base, ldsb + dstC[k]);
    if (w < 2)
        gld16(xr + srcE[3] + g0base, ldsb + dstC[3]);
    __syncthreads();

    for (int wi = 0; wi <= u; ++wi) {
        int cur = wi & 1;
        if (wi < u) {                    // DMA next window into other buffer
            int g0n = g0base + ((wi + 1) << 6);
            char* bufn = ldsb + (cur ^ 1)*BUFB;
            #pragma unroll
            for (int k = 0; k < 3; ++k)
                gld16(xr + srcE[k] + g0n, bufn + dstC[k]);
            if (w < 2)
                gld16(xr + srcE[3] + g0n, bufn + dstC[3]);
        }
        bool full = (wi < u);            // deltas 2,3 inactive on last window
        int dcw = wi << 3;
        const char* rbase = ldsb + cur*BUFB + bbb;

        // A-fragment 2-stage prefetch across cii
        bf16x8 av0, av1, av2, av3, nv0, nv1, nv2, nv3;
        {
            const uint16_t* aB = Wt + (((cig*WT_CH + dcw + hi)*NCO + n) << 3);
            av0 = *(const bf16x8*)(aB);
            av1 = *(const bf16x8*)(aB + 512);
            av2 = *(const bf16x8*)(aB + 1024);
            av3 = *(const bf16x8*)(aB + 1536);
        }
        #pragma unroll
        for (int cii = 0; cii < 4; ++cii) {
            if (cii < 3) {
                const uint16_t* aN = Wt + (((((cii+1)*8 + cig)*WT_CH + dcw + hi)*NCO + n) << 3);
                nv0 = *(const bf16x8*)(aN);
                nv1 = *(const bf16x8*)(aN + 512);
                nv2 = *(const bf16x8*)(aN + 1024);
                nv3 = *(const bf16x8*)(aN + 1536);
            }
            const char* pbase = rbase + cii*(8*CIB);

            #define RDBB(MM) union { uint32_t u_[4]; bf16x8 v; } bb; { \
                const char* pp = pbase + ((MM) << 5); \
                bb.u_[0] = *(const uint32_t*)(pp); \
                bb.u_[1] = *(const uint32_t*)(pp + 4); \
                bb.u_[2] = *(const uint32_t*)(pp + 8); \
                bb.u_[3] = *(const uint32_t*)(pp + 12); }

            { RDBB(0) acc0 = __builtin_amdgcn_mfma_f32_32x32x16_bf16(av0, bb.v, acc0, 0,0,0); }
            { RDBB(1) acc0 = __builtin_amdgcn_mfma_f32_32x32x16_bf16(av1, bb.v, acc0, 0,0,0); }
            { RDBB(2) acc0 = __builtin_amdgcn_mfma_f32_32x32x16_bf16(av2, bb.v, acc0, 0,0,0);
                      acc1 = __builtin_amdgcn_mfma_f32_32x32x16_bf16(av0, bb.v, acc1, 0,0,0); }
            { RDBB(3) acc0 = __builtin_amdgcn_mfma_f32_32x32x16_bf16(av3, bb.v, acc0, 0,0,0);
                      acc1 = __builtin_amdgcn_mfma_f32_32x32x16_bf16(av1, bb.v, acc1, 0,0,0); }
            { RDBB(4) acc1 = __builtin_amdgcn_mfma_f32_32x32x16_bf16(av2, bb.v, acc1, 0,0,0);
              if (full) acc2 = __builtin_amdgcn_mfma_f32_32x32x16_bf16(av0, bb.v, acc2, 0,0,0); }
            { RDBB(5) acc1 = __builtin_amdgcn_mfma_f32_32x32x16_bf16(av3, bb.v, acc1, 0,0,0);
              if (full) acc2 = __builtin_amdgcn_mfma_f32_32x32x16_bf16(av1, bb.v, acc2, 0,0,0); }
            if (full) {
                { RDBB(6) acc2 = __builtin_amdgcn_mfma_f32_32x32x16_bf16(av2, bb.v, acc2, 0,0,0);
                          acc3 = __builtin_amdgcn_mfma_f32_32x32x16_bf16(av0, bb.v, acc3, 0,0,0); }
                { RDBB(7) acc2 = __builtin_amdgcn_mfma_f32_32x32x16_bf16(av3, bb.v, acc2, 0,0,0);
                          acc3 = __builtin_amdgcn_mfma_f32_32x32x16_bf16(av1, bb.v, acc3, 0,0,0); }
                { RDBB(8) acc3 = __builtin_amdgcn_mfma_f32_32x32x16_bf16(av2, bb.v, acc3, 0,0,0); }
                { RDBB(9) acc3 = __builtin_amdgcn_mfma_f32_32x32x16_bf16(av3, bb.v, acc3, 0,0,0); }
            }
            #undef RDBB
            if (cii < 3) { av0 = nv0; av1 = nv1; av2 = nv2; av3 = nv3; }
        }
        __syncthreads();                 // drains DMA (vmcnt) + read/write fence
    }

    // ---- reduce across 8 ci-waves + epilogue, one delta at a time ----
    #pragma unroll
    for (int dlt = 0; dlt < 4; ++dlt) {
        f32x16 a = (dlt == 0) ? acc0 : (dlt == 1) ? acc1 : (dlt == 2) ? acc2 : acc3;
        __syncthreads();
        if (w < 4) {
            #pragma unroll
            for (int r = 0; r < 16; ++r)
                red[(w*16 + r)*64 + lane] = a[r];
        }
        __syncthreads();
        if (w >= 4) {
            #pragma unroll
            for (int r = 0; r < 16; ++r)
                red[((w-4)*16 + r)*64 + lane] += a[r];
        }
        __syncthreads();
        int t0 = (th - dlt) << 5;
        #pragma unroll
        for (int h = 0; h < 2; ++h) {
            int e = tid + (h << 9);
            int lane_e = e & 63;
            int reg = e >> 6;
            float s = 0.f;
            #pragma unroll
            for (int ww = 0; ww < 4; ++ww) s += red[(ww*16 + reg)*64 + lane_e];
            int co = (reg & 3) + ((reg >> 2) << 3) + ((lane_e >> 5) << 2);
            int t = t0 + (lane_e & 31);
            out[(b*NCO + co)*T + t] = s + bias[co];
        }
    }
}

extern "C" void kernel_launch(void* const* d_in, const int* in_sizes, int n_in,
                              void* d_out, int out_size, void* d_ws, size_t ws_size,
                              hipStream_t stream)
{
    const float* x       = (const float*)d_in[0];
    const float* rel_pos = (const float*)d_in[1];
    const float* w1  = (const float*)d_in[2];
    const float* b1  = (const float*)d_in[3];
    const float* om1 = (const float*)d_in[4];
    const float* w2  = (const float*)d_in[5];
    const float* b2  = (const float*)d_in[6];
    const float* om2 = (const float*)d_in[7];
    const float* w3  = (const float*)d_in[8];
    const float* b3  = (const float*)d_in[9];
    const float* bias = (const float*)d_in[10];
    float* out = (float*)d_out;
    char* ws = (char*)d_ws;
    uint16_t* Wt  = (uint16_t*)(ws + WT_OFF);
    uint16_t* xrp = (uint16_t*)(ws + XR_OFF);
    uint16_t* xrs = (uint16_t*)(ws + XRS_OFF);

    hipLaunchKernelGGL(gen_w, dim3(WT_CH*8), dim3(256), 0, stream,
                       rel_pos, w1, b1, om1, w2, b2, om2, w3, b3, Wt);
    int n2 = NB*NCI*GR;
    hipLaunchKernelGGL(gen_x, dim3((n2+255)/256), dim3(256), 0, stream, x, xrp, xrs);
    hipLaunchKernelGGL(conv, dim3(NB*16), dim3(512), 0, stream, Wt, xrp, bias, out);
}

// Round 10
// 167.392 us; speedup vs baseline: 1.0846x; 1.0846x over previous
//
#include <hip/hip_runtime.h>
#include <hip/hip_bf16.h>
#include <stdint.h>

typedef short bf16x8 __attribute__((ext_vector_type(8)));
typedef float f32x16 __attribute__((ext_vector_type(16)));

#define T 2048
#define KLEN 2049
#define DK 32
#define NCO 32
#define NCI 32
#define NB 32

#define GR 2216          // padded reversed row length (covers g up to 2184)
#define SREF 2055        // x[s] lives at g = SREF - s (xr); xrs[g] = xr[g+1]
#define WT_CH 257        // 8-wide d-chunks, d in [0,2056)
#define WT_ELEMS (NCI*WT_CH*NCO*8)
#define XR_ELEMS (NB*NCI*GR)

#define WT_OFF 0
#define XR_OFF (WT_ELEMS*2)
#define XRS_OFF (XR_OFF + XR_ELEMS*2)

#define CIB 528          // bytes per ci row: 33 x 16B granules (264 elems)
#define GPC 1056         // real granules per parity copy (32 ci x 33)
#define GPCP 1088        // padded to 17 x 64-chunks (no copy-straddle)
#define CPYB 17472       // parity-copy stride: >=GPCP*16, ==64 mod 128 (bank de-alias)
#define BUFB (2*CPYB)    // 34944 per double-buffer
#define LDS_TOT (2*BUFB) // 69888 -> 2 blocks/CU; reduce reuses buf0

// ---------------- kernel-generation: SIREN -> flipped, fragment-layout W ----
__global__ __launch_bounds__(256) void gen_w(
    const float* __restrict__ rel_pos,
    const float* __restrict__ w1, const float* __restrict__ b1, const float* __restrict__ om1,
    const float* __restrict__ w2, const float* __restrict__ b2, const float* __restrict__ om2,
    const float* __restrict__ w3, const float* __restrict__ b3,
    uint16_t* __restrict__ Wt)
{
    int d = blockIdx.x;          // flipped lag, 0..2055
    int tid = threadIdx.x;
    if (d >= KLEN) {             // zero pad region
        for (int r = 0; r < 4; ++r) {
            int coci = tid + 256*r;
            int co = coci >> 5, ci = coci & 31;
            Wt[(((ci*WT_CH + (d>>3))*NCO + co)<<3) + (d&7)] = 0;
        }
        return;
    }
    int kk = 2048 - d;
    float pos = rel_pos[kk];
    __shared__ float h1[DK];
    __shared__ float h2[DK];
    if (tid < DK) h1[tid] = sinf(om1[0]*(w1[tid]*pos + b1[tid]));
    __syncthreads();
    if (tid < DK) {
        float a = b2[tid];
        for (int j = 0; j < DK; ++j) a += w2[tid*DK+j]*h1[j];
        h2[tid] = sinf(om2[0]*a);
    }
    __syncthreads();
    for (int r = 0; r < 4; ++r) {
        int coci = tid + 256*r;
        float a = b3[coci];
        for (int j = 0; j < DK; ++j) a += w3[coci*DK+j]*h2[j];
        int co = coci >> 5, ci = coci & 31;
        __hip_bfloat16 hv = __float2bfloat16(a);
        Wt[(((ci*WT_CH + (d>>3))*NCO + co)<<3) + (d&7)] = *(uint16_t*)&hv;
    }
}

// ---------------- x -> reversed, zero-padded bf16 (plus shifted copy) -------
__global__ __launch_bounds__(256) void gen_x(const float* __restrict__ x,
                                             uint16_t* __restrict__ xr,
                                             uint16_t* __restrict__ xrs)
{
    int idx = blockIdx.x*256 + threadIdx.x;
    if (idx >= NB*NCI*GR) return;
    int row = idx / GR;          // b*32+ci
    int g = idx - row*GR;
    int s = SREF - g;
    float v  = (s  >= 0 && s  < T) ? x[row*T + s]  : 0.f;
    int s2 = s - 1;              // value at g+1
    float v2 = (s2 >= 0 && s2 < T) ? x[row*T + s2] : 0.f;
    __hip_bfloat16 hv = __float2bfloat16(v);
    __hip_bfloat16 hv2 = __float2bfloat16(v2);
    xr[idx]  = *(uint16_t*)&hv;
    xrs[idx] = *(uint16_t*)&hv2;
}

__device__ __forceinline__ void gld16(const uint16_t* g, char* l)
{
    typedef const __attribute__((address_space(1))) uint32_t GU;
    typedef __attribute__((address_space(3))) uint32_t LU;
    __builtin_amdgcn_global_load_lds((GU*)g, (LU*)l, 16, 0, 0);
}

// ---------------- causal conv: implicit-Toeplitz MFMA GEMM -------------------
// K=4 tau-chain, 128-element k-windows. One chain per block; grid 512 = 2
// blocks/CU. Pairing: block c (long chain, 16-p windows) + c+256 (short, p+1)
// co-resident -> 17 window-units per CU. b in low 5 bits -> XCD locality.
// Per window & cii: 14 staged fragments (MM=c+2*delta) serve 32 MFMAs.
__global__ __launch_bounds__(512, 4) void conv(
    const uint16_t* __restrict__ Wt, const uint16_t* __restrict__ xr,
    const float* __restrict__ bias, float* __restrict__ out)
{
    __shared__ uint4 lds4[LDS_TOT/16];
    char* ldsb = (char*)lds4;
    float* red = (float*)lds4;            // overlaps buf0; used after final barrier
    int tid = threadIdx.x;
    int b = blockIdx.x & 31;
    int q = blockIdx.x >> 5;              // 0..15
    int p = q & 7;
    int th = (q < 8) ? (63 - (p << 2)) : ((p << 2) + 3);   // long B / short A
    int nw = (th + 1) >> 2;                                // 128-elem windows
    int g0base = 2016 - (th << 5);
    int w = tid >> 6, lane = tid & 63, n = lane & 31, hi = lane >> 5;
    int cig = w;

    // staging: 2176 idx = 2 copies x 1088 (1056 real + 32 pad); 64-idx chunks,
    // wave-uniform LDS dest (linear), per-lane global source.
    int srcE[5], dstC[5];
    #pragma unroll
    for (int k = 0; k < 5; ++k) {
        int gi = tid + (k << 9);
        if (gi < 2176) {
            int cpy = gi >= GPCP;
            int j = gi - cpy*GPCP;
            dstC[k] = cpy*CPYB + (j << 4);
            if (j < GPC) {
                int ci = (j*1986) >> 16;     // j/33 for j<1056
                int qq = j - ci*33;
                srcE[k] = (cpy ? XR_ELEMS : 0) + (b*NCI + ci)*GR + (qq << 3);
            } else srcE[k] = 0;              // pad granule: safe dummy source
        } else { srcE[k] = 0; dstC[k] = -1; }
    }

    // B-read base: o = (39 - n + 8*hi) + 16*MM; byte = ci*CIB + par*CPYB + 2*(o-par)
    int obase = 39 - n + (hi << 3);
    int par = obase & 1;
    int bbb = cig*CIB + par*CPYB + ((obase - par) << 1);

    f32x16 acc0, acc1, acc2, acc3;
    #pragma unroll
    for (int r = 0; r < 16; ++r) { acc0[r]=0.f; acc1[r]=0.f; acc2[r]=0.f; acc3[r]=0.f; }

    #define STAGE(BUF, GOFF) { \
        _Pragma("unroll") \
        for (int k = 0; k < 5; ++k) \
            if (dstC[k] >= 0) gld16(xr + srcE[k] + (GOFF), (BUF) + dstC[k]); }

    // prologue: DMA window 0 into buf0
    STAGE(ldsb, g0base)
    __syncthreads();

    for (int wi = 0; wi < nw; ++wi) {
        int cur = wi & 1;
        if (wi + 1 < nw) {                   // DMA next window into other buffer
            char* bufn = ldsb + (cur ^ 1)*BUFB;
            int g0n = g0base + ((wi + 1) << 7);
            STAGE(bufn, g0n)
        }
        int dcw = wi << 4;
        const char* rbase = ldsb + cur*BUFB + bbb;

        #pragma unroll
        for (int cii = 0; cii < 4; ++cii) {
            int ci = (cii << 3) + cig;
            const uint16_t* aB = Wt + (((ci*WT_CH + dcw + hi)*NCO + n) << 3);
            bf16x8 av0 = *(const bf16x8*)(aB);
            bf16x8 av1 = *(const bf16x8*)(aB + 512);
            bf16x8 av2 = *(const bf16x8*)(aB + 1024);
            bf16x8 av3 = *(const bf16x8*)(aB + 1536);
            bf16x8 av4 = *(const bf16x8*)(aB + 2048);
            bf16x8 av5 = *(const bf16x8*)(aB + 2560);
            bf16x8 av6 = *(const bf16x8*)(aB + 3072);
            bf16x8 av7 = *(const bf16x8*)(aB + 3584);
            const char* pbase = rbase + cii*(8*CIB);

            #define RDBB(MM) union { uint32_t u_[4]; bf16x8 v; } bb; { \
                const char* pp = pbase + ((MM) << 5); \
                bb.u_[0] = *(const uint32_t*)(pp); \
                bb.u_[1] = *(const uint32_t*)(pp + 4); \
                bb.u_[2] = *(const uint32_t*)(pp + 8); \
                bb.u_[3] = *(const uint32_t*)(pp + 12); }
            #define MF(AC, AV) AC = __builtin_amdgcn_mfma_f32_32x32x16_bf16(AV, bb.v, AC, 0,0,0);

            { RDBB(0)  MF(acc0, av0) }
            { RDBB(1)  MF(acc0, av1) }
            { RDBB(2)  MF(acc0, av2) MF(acc1, av0) }
            { RDBB(3)  MF(acc0, av3) MF(acc1, av1) }
            { RDBB(4)  MF(acc0, av4) MF(acc1, av2) MF(acc2, av0) }
            { RDBB(5)  MF(acc0, av5) MF(acc1, av3) MF(acc2, av1) }
            { RDBB(6)  MF(acc0, av6) MF(acc1, av4) MF(acc2, av2) MF(acc3, av0) }
            { RDBB(7)  MF(acc0, av7) MF(acc1, av5) MF(acc2, av3) MF(acc3, av1) }
            { RDBB(8)  MF(acc1, av6) MF(acc2, av4) MF(acc3, av2) }
            { RDBB(9)  MF(acc1, av7) MF(acc2, av5) MF(acc3, av3) }
            { RDBB(10) MF(acc2, av6) MF(acc3, av4) }
            { RDBB(11) MF(acc2, av7) MF(acc3, av5) }
            { RDBB(12) MF(acc3, av6) }
            { RDBB(13) MF(acc3, av7) }
            #undef MF
            #undef RDBB
        }
        __syncthreads();                 // drains DMA (vmcnt) + read/write fence
    }
    #undef STAGE

    // ---- reduce across 8 ci-waves + epilogue, one delta at a time ----
    #pragma unroll
    for (int dlt = 0; dlt < 4; ++dlt) {
        f32x16 a = (dlt == 0) ? acc0 : (dlt == 1) ? acc1 : (dlt == 2) ? acc2 : acc3;
        __syncthreads();
        if (w < 4) {
            #pragma unroll
            for (int r = 0; r < 16; ++r)
                red[(w*16 + r)*64 + lane] = a[r];
        }
        __syncthreads();
        if (w >= 4) {
            #pragma unroll
            for (int r = 0; r < 16; ++r)
                red[((w-4)*16 + r)*64 + lane] += a[r];
        }
        __syncthreads();
        int t0 = (th - dlt) << 5;
        #pragma unroll
        for (int h = 0; h < 2; ++h) {
            int e = tid + (h << 9);
            int lane_e = e & 63;
            int reg = e >> 6;
            float s = 0.f;
            #pragma unroll
            for (int ww = 0; ww < 4; ++ww) s += red[(ww*16 + reg)*64 + lane_e];
            int co = (reg & 3) + ((reg >> 2) << 3) + ((lane_e >> 5) << 2);
            int t = t0 + (lane_e & 31);
            out[(b*NCO + co)*T + t] = s + bias[co];
        }
    }
}

extern "C" void kernel_launch(void* const* d_in, const int* in_sizes, int n_in,
                              void* d_out, int out_size, void* d_ws, size_t ws_size,
                              hipStream_t stream)
{
    const float* x       = (const float*)d_in[0];
    const float* rel_pos = (const float*)d_in[1];
    const float* w1  = (const float*)d_in[2];
    const float* b1  = (const float*)d_in[3];
    const float* om1 = (const float*)d_in[4];
    const float* w2  = (const float*)d_in[5];
    const float* b2  = (const float*)d_in[6];
    const float* om2 = (const float*)d_in[7];
    const float* w3  = (const float*)d_in[8];
    const float* b3  = (const float*)d_in[9];
    const float* bias = (const float*)d_in[10];
    float* out = (float*)d_out;
    char* ws = (char*)d_ws;
    uint16_t* Wt  = (uint16_t*)(ws + WT_OFF);
    uint16_t* xrp = (uint16_t*)(ws + XR_OFF);
    uint16_t* xrs = (uint16_t*)(ws + XRS_OFF);

    hipLaunchKernelGGL(gen_w, dim3(WT_CH*8), dim3(256), 0, stream,
                       rel_pos, w1, b1, om1, w2, b2, om2, w3, b3, Wt);
    int n2 = NB*NCI*GR;
    hipLaunchKernelGGL(gen_x, dim3((n2+255)/256), dim3(256), 0, stream, x, xrp, xrs);
    hipLaunchKernelGGL(conv, dim3(NB*16), dim3(512), 0, stream, Wt, xrp, bias, out);
}